// Round 7
// baseline (954.846 us; speedup 1.0000x reference)
//
#include <hip/hip_runtime.h>

#define IH 512
#define IW 512
#define OH 510
#define OW 510
#define NB 32
#define KO 16

typedef float f32x4 __attribute__((ext_vector_type(4)));
typedef float f32x2 __attribute__((ext_vector_type(2)));

// Grid = (row-octet x, plane y), x-fastest dispatch -> resident ~2K blocks
// cover ~32 consecutive planes (~2 images): compact sliding write window AND
// L2-resident x rows (all XCDs chew the same 1-2 images).
// Thread = 16 output cols of ONE row: 12-15 b128 loads + 4 b128 stores
// (1.19 VMEM insts/output, vs champion R3's 1.56). Alignment: row stride
// 2040B % 16 == 8, so odd rows use column phase +2 (j = 16*tc + 2) making
// every b128 load/store 16B-aligned for both parities.
__global__ __launch_bounds__(256) void conv3x3_k16_kernel(
    const float* __restrict__ x,
    const float* __restrict__ k,
    float* __restrict__ out)
{
    const int p = blockIdx.y;           // plane = n*16 + o
    const int o = p & 15;
    const int n = p >> 4;
    const int t = threadIdx.x;
    const int rowg = t >> 5;            // 0..7 row within octet
    const int tc = t & 31;              // col-group
    const int i = blockIdx.x * 8 + rowg;
    if (i >= OH) return;
    const int odd = i & 1;
    const int ph = odd ? 2 : 0;
    const int c0 = tc * 16;             // x base col (16B aligned)
    const int jb = c0 + ph;             // output base col
    const bool lastg = (tc == 31);

    // 9 weights, thread-uniform -> SGPRs
    float w[9];
#pragma unroll
    for (int q = 0; q < 9; ++q) w[q] = k[o * 9 + q];

    const float* xbase = x + ((size_t)n * IH + i) * IW + c0;

    // Load x rows i..i+2, cols c0..c0+19 (lastg: c0..c0+15), all 16B aligned.
    float xv[3][20];
#pragma unroll
    for (int r = 0; r < 3; ++r) {
        const float* xr = xbase + r * IW;
#pragma unroll
        for (int q = 0; q < 4; ++q) {
            const f32x4 v = *reinterpret_cast<const f32x4*>(xr + 4 * q);
            xv[r][4 * q + 0] = v[0]; xv[r][4 * q + 1] = v[1];
            xv[r][4 * q + 2] = v[2]; xv[r][4 * q + 3] = v[3];
        }
        if (!lastg) {
            const f32x4 v = *reinterpret_cast<const f32x4*>(xr + 16);
            xv[r][16] = v[0]; xv[r][17] = v[1];
            xv[r][18] = v[2]; xv[r][19] = v[3];
        } else {
            xv[r][16] = 0.0f; xv[r][17] = 0.0f;
            xv[r][18] = 0.0f; xv[r][19] = 0.0f;
        }
    }

    // acc[c] = out(i, jb+c); x col of tap tt = jb+c+tt = c0 + (c+ph+tt)
    float acc[16];
#pragma unroll
    for (int c = 0; c < 16; ++c) {
        float a = 0.0f;
#pragma unroll
        for (int r = 0; r < 3; ++r)
#pragma unroll
            for (int tt = 0; tt < 3; ++tt)
                a = fmaf(xv[r][c + ph + tt], w[r * 3 + tt], a);
        acc[c] = a;
    }

    float* orow = out + ((size_t)p * OH + i) * OW;

    if (!lastg) {
        // 16 outputs at jb..jb+15 (16B-aligned stores for both parities)
#pragma unroll
        for (int q = 0; q < 4; ++q) {
            f32x4 v;
            v[0] = acc[4 * q + 0]; v[1] = acc[4 * q + 1];
            v[2] = acc[4 * q + 2]; v[3] = acc[4 * q + 3];
            __builtin_nontemporal_store(v,
                reinterpret_cast<f32x4*>(orow + jb + 4 * q));
        }
        if (odd && tc == 0) {
            // head cols j=0,1 (odd rows): x cols 0..3 are xv[r][0..3]
            float h0 = 0.0f, h1 = 0.0f;
#pragma unroll
            for (int r = 0; r < 3; ++r)
#pragma unroll
                for (int tt = 0; tt < 3; ++tt) {
                    h0 = fmaf(xv[r][tt],     w[r * 3 + tt], h0);
                    h1 = fmaf(xv[r][tt + 1], w[r * 3 + tt], h1);
                }
            f32x2 h; h[0] = h0; h[1] = h1;
            __builtin_nontemporal_store(h, reinterpret_cast<f32x2*>(orow));
        }
    } else {
        // even rows: j=496..509 (14 cols); odd rows: j=498..509 (12 cols)
#pragma unroll
        for (int q = 0; q < 3; ++q) {
            f32x4 v;
            v[0] = acc[4 * q + 0]; v[1] = acc[4 * q + 1];
            v[2] = acc[4 * q + 2]; v[3] = acc[4 * q + 3];
            __builtin_nontemporal_store(v,
                reinterpret_cast<f32x4*>(orow + jb + 4 * q));
        }
        if (!odd) {
            f32x2 v; v[0] = acc[12]; v[1] = acc[13];
            __builtin_nontemporal_store(v,
                reinterpret_cast<f32x2*>(orow + jb + 12));
        }
    }
}

extern "C" void kernel_launch(void* const* d_in, const int* in_sizes, int n_in,
                              void* d_out, int out_size, void* d_ws, size_t ws_size,
                              hipStream_t stream) {
    const float* x   = (const float*)d_in[0];
    const float* ker = (const float*)d_in[1];
    float* out       = (float*)d_out;

    dim3 grid((OH + 7) / 8, NB * KO);   // (64 row-octets, 512 planes)
    dim3 block(256);
    conv3x3_k16_kernel<<<grid, block, 0, stream>>>(x, ker, out);
}

// Round 8
// 176.148 us; speedup vs baseline: 5.4207x; 5.4207x over previous
//
#include <hip/hip_runtime.h>

#define IH 512
#define IW 512
#define OH 510
#define OW 510
#define NB 32
#define KO 16
#define TPB 4
#define BLOCKS 2040   // 2040 * 4 = 8160 = 32 images * 255 row-pairs

typedef float f32x4 __attribute__((ext_vector_type(4)));
typedef float f32x2 __attribute__((ext_vector_type(2)));

// Persistent-ish blocks: each block processes TPB=4 consecutive (n, row-pair)
// tiles with a 2-deep software pipeline (issue next tile's loads before the
// current tile's FMA+stores). Store shape is the proven R3 pattern: each wave
// store instruction is lane-contiguous (lane i at base+16B*i -> full 128B
// lines; R7 proved strided-lane stores cause 5.7x RMW write amplification).
__device__ __forceinline__ void tile_ptrs(int tile, int half, int tt, bool tail,
                                          const float* __restrict__ x,
                                          float* __restrict__ out,
                                          const float** xr, float** op)
{
    const int n  = tile / 255;
    const int rp = tile - n * 255;
    const int i  = 2 * rp + half;
    // Even rows: j=4*tt (tail 508); odd rows: j=4*tt+2 (tail 0).
    // Keeps (i*OW+j)*4 % 16 == 0 for all full threads (row stride 2040B).
    int j;
    if ((i & 1) == 0) j = tail ? 508 : 4 * tt;
    else              j = tail ? 0   : 4 * tt + 2;
    *xr = x + ((size_t)n * IH + i) * IW + j;
    *op = out + (((size_t)n * KO) * OH + i) * OW + j;
}

__device__ __forceinline__ void load_tile(const float* __restrict__ xr,
                                          bool tail, float v[3][6])
{
#pragma unroll
    for (int r = 0; r < 3; ++r) {
        const float2 a = *reinterpret_cast<const float2*>(xr + r * IW);
        const float2 b = *reinterpret_cast<const float2*>(xr + r * IW + 2);
        v[r][0] = a.x; v[r][1] = a.y; v[r][2] = b.x; v[r][3] = b.y;
        if (!tail) {
            const float2 c = *reinterpret_cast<const float2*>(xr + r * IW + 4);
            v[r][4] = c.x; v[r][5] = c.y;
        } else {
            v[r][4] = 0.0f; v[r][5] = 0.0f;
        }
    }
}

__global__ __launch_bounds__(256, 4) void conv3x3_k16_kernel(
    const float* __restrict__ x,
    const float* __restrict__ k,
    float* __restrict__ out)
{
    const int t    = threadIdx.x;
    const int half = t >> 7;            // row within pair
    const int tt   = t & 127;
    const bool tail = (tt == 127);

    const int tile0 = blockIdx.x * TPB;

    const float* xr; float* op;
    tile_ptrs(tile0, half, tt, tail, x, out, &xr, &op);
    float xv[3][6];
    load_tile(xr, tail, xv);

#pragma unroll 1
    for (int q = 0; q < TPB; ++q) {
        const float* xrn; float* opn = nullptr;
        float xvn[3][6];
        const bool more = (q + 1 < TPB);
        if (more) {
            // Issue next tile's loads FIRST: they complete under the FMA block.
            tile_ptrs(tile0 + q + 1, half, tt, tail, x, out, &xrn, &opn);
            load_tile(xrn, tail, xvn);
        }

#pragma unroll
        for (int o = 0; o < KO; ++o) {
            float a0 = 0.f, a1 = 0.f, a2 = 0.f, a3 = 0.f;
#pragma unroll
            for (int r = 0; r < 3; ++r)
#pragma unroll
                for (int c = 0; c < 3; ++c) {
                    const float kv = k[(o * 3 + r) * 3 + c];  // uniform s_load
                    a0 = fmaf(xv[r][c],     kv, a0);
                    a1 = fmaf(xv[r][c + 1], kv, a1);
                    a2 = fmaf(xv[r][c + 2], kv, a2);
                    a3 = fmaf(xv[r][c + 3], kv, a3);
                }
            float* p = op + (size_t)o * (OH * OW);
            if (!tail) {
                f32x4 v; v[0] = a0; v[1] = a1; v[2] = a2; v[3] = a3;
                __builtin_nontemporal_store(v, reinterpret_cast<f32x4*>(p));
            } else {
                f32x2 v; v[0] = a0; v[1] = a1;
                __builtin_nontemporal_store(v, reinterpret_cast<f32x2*>(p));
            }
        }

        if (more) {
            xr = xrn; op = opn;
#pragma unroll
            for (int r = 0; r < 3; ++r)
#pragma unroll
                for (int c = 0; c < 6; ++c) xv[r][c] = xvn[r][c];
        }
    }
}

extern "C" void kernel_launch(void* const* d_in, const int* in_sizes, int n_in,
                              void* d_out, int out_size, void* d_ws, size_t ws_size,
                              hipStream_t stream) {
    const float* x   = (const float*)d_in[0];
    const float* ker = (const float*)d_in[1];
    float* out       = (float*)d_out;

    dim3 grid(BLOCKS);
    dim3 block(256);
    conv3x3_k16_kernel<<<grid, block, 0, stream>>>(x, ker, out);
}

// Round 9
// 154.684 us; speedup vs baseline: 6.1729x; 1.1388x over previous
//
#include <hip/hip_runtime.h>

#define IH 512
#define IW 512
#define OH 510
#define OW 510
#define NB 32
#define KO 16
#define OHW (OH * OW)

typedef float f32x4 __attribute__((ext_vector_type(4)));
typedef float f32x2 __attribute__((ext_vector_type(2)));

// R3 structure + anti-serialization store phase.
// Theory: R3's VGPR_Count=20 forced the compiler to recycle store-data regs
// across the 16 plane stores; CDNA stores read data VGPRs after issue, so
// each reuse needs s_waitcnt vmcnt -> only ~1-2 stores in flight per wave ->
// chip-wide in-flight writes ~12MB -> Little's-law cap ~3.6 TB/s (observed).
// Fix: compute ALL 16x4 accumulators first, sched_barrier(0), then 16
// back-to-back stores from 64 distinct VGPRs (no reuse -> no waits -> 16KB
// in flight per wave). launch_bounds(256,4): 128-VGPR budget, ~92 needed.
__global__ __launch_bounds__(256, 4) void conv3x3_k16_kernel(
    const float* __restrict__ x,
    const float* __restrict__ k,
    float* __restrict__ out)
{
    const int bid = blockIdx.x;
    const int n  = bid / (OH / 2);            // image
    const int i0 = (bid - n * (OH / 2)) * 2;  // even base row
    const int t  = threadIdx.x;
    const int half = t >> 7;                  // row within pair
    const int tt = t & 127;
    const int i  = i0 + half;                 // output row
    const bool tail = (tt == 127);

    // Even rows: j=4tt (tail 508); odd rows: j=4tt+2 (tail 0).
    // Keeps (i*OW+j)*4 % 16 == 0 for all full threads (row stride 2040B).
    int j;
    if ((i & 1) == 0) j = tail ? 508 : 4 * tt;
    else              j = tail ? 0   : 4 * tt + 2;

    const float* xr = x + ((size_t)n * IH + i) * IW + j;

    // Phase 1: load 3 rows x 6 cols (tail: 3 x 4), 8B-aligned float2s.
    float xv[3][6];
#pragma unroll
    for (int r = 0; r < 3; ++r) {
        const float2 a = *reinterpret_cast<const float2*>(xr + r * IW);
        const float2 b = *reinterpret_cast<const float2*>(xr + r * IW + 2);
        xv[r][0] = a.x; xv[r][1] = a.y; xv[r][2] = b.x; xv[r][3] = b.y;
        if (!tail) {
            const float2 c = *reinterpret_cast<const float2*>(xr + r * IW + 4);
            xv[r][4] = c.x; xv[r][5] = c.y;
        } else {
            xv[r][4] = 0.0f; xv[r][5] = 0.0f;
        }
    }

    // Phase 2: compute ALL accumulators (64 distinct VGPRs, static indexing).
    float acc[KO][4];
#pragma unroll
    for (int o = 0; o < KO; ++o) {
        float a0 = 0.f, a1 = 0.f, a2 = 0.f, a3 = 0.f;
#pragma unroll
        for (int r = 0; r < 3; ++r)
#pragma unroll
            for (int c = 0; c < 3; ++c) {
                const float kv = k[(o * 3 + r) * 3 + c];  // uniform -> s_load
                a0 = fmaf(xv[r][c],     kv, a0);
                a1 = fmaf(xv[r][c + 1], kv, a1);
                a2 = fmaf(xv[r][c + 2], kv, a2);
                a3 = fmaf(xv[r][c + 3], kv, a3);
            }
        acc[o][0] = a0; acc[o][1] = a1; acc[o][2] = a2; acc[o][3] = a3;
    }

    // Pin the phase boundary: all accs live here; stores emitted as one run.
    __builtin_amdgcn_sched_barrier(0);

    // Phase 3: 16 stores, shared per-thread offset + uniform plane bases
    // (SADDR form: one voffset VGPR, per-o SGPR base -> no addr-reg reuse).
    float* ob = out + ((size_t)n * KO) * OHW + (size_t)i0 * OW;  // uniform
    const int toff = half * OW + j;                               // per-thread
#pragma unroll
    for (int o = 0; o < KO; ++o) {
        float* p = ob + (size_t)o * OHW + toff;
        if (!tail) {
            f32x4 v; v[0] = acc[o][0]; v[1] = acc[o][1];
                     v[2] = acc[o][2]; v[3] = acc[o][3];
            __builtin_nontemporal_store(v, reinterpret_cast<f32x4*>(p));
        } else {
            f32x2 v; v[0] = acc[o][0]; v[1] = acc[o][1];
            __builtin_nontemporal_store(v, reinterpret_cast<f32x2*>(p));
        }
    }
}

extern "C" void kernel_launch(void* const* d_in, const int* in_sizes, int n_in,
                              void* d_out, int out_size, void* d_ws, size_t ws_size,
                              hipStream_t stream) {
    const float* x   = (const float*)d_in[0];
    const float* ker = (const float*)d_in[1];
    float* out       = (float*)d_out;

    dim3 grid(NB * (OH / 2));   // 8160 blocks: (image, row-pair)
    dim3 block(256);
    conv3x3_k16_kernel<<<grid, block, 0, stream>>>(x, ker, out);
}